// Round 2
// baseline (253.966 us; speedup 1.0000x reference)
//
#include <hip/hip_runtime.h>
#include <stdint.h>

#define TT 512
#define BT 4     // 4096/4 = 1024 wgs -> 4 wgs/CU -> 4 waves/SIMD
#define XSTR 516 // x row stride (floats)

typedef float    f32x4 __attribute__((ext_vector_type(4)));
typedef short    s16x8 __attribute__((ext_vector_type(8)));
typedef _Float16 f16x8 __attribute__((ext_vector_type(8)));

#define MFMA_F16(A, B, C) \
    __builtin_amdgcn_mfma_f32_16x16x32_f16( \
        __builtin_bit_cast(f16x8, (A)), (B), (C), 0, 0, 0)

#define LOG2E  1.442695040888963f
#define LOG2E2 2.885390081777927f

// R10 (resubmit; prior bench died to container infra, no signal):
// BT=4, 4 wgs/CU (16 waves/CU) for chain-latency coverage.
// Dense h exchange: hbuf[dbuf][32 slots][8 f16], slot = (k>>3)*4 + batch.
// A-read duplicates batch (n16>>2) onto all 4 rows of each quad -> no
// zeroing, no swizzle; D rows 4q..4q+3 all hold batch q, use reg 0.
// Write: 1 ds_write_b16/lane, bank = 16*(n16>>3)+4*quad+((n16&7)>>1),
// bijective over 32 banks (conflict-free). R-gate MFMA C-chain split
// (parallel MFMAs + add). h-update uses carried (h-1): hn = z*(2*rn+hm1)+n.
__global__ __launch_bounds__(256, 4) void gru_scan_kernel(
    const float* __restrict__ x,     // (4096, 512, 1)
    const float* __restrict__ Wih,   // (192, 1)
    const float* __restrict__ Whh,   // (192, 64)
    const float* __restrict__ bih,   // (192)
    const float* __restrict__ bhh,   // (192)
    const float* __restrict__ Wout,  // (1, 64)
    const float* __restrict__ bout,  // (1)
    float* __restrict__ out)         // (4096, 1)
{
    __shared__ __align__(16) float xs[BT * XSTR];   // 8.25 KB
    __shared__ __align__(16) short hbuf[2][256];    // 1 KB total
    __shared__ float outp[4][BT];

    const int tid  = threadIdx.x;
    const int w    = tid >> 6;
    const int L    = tid & 63;
    const int n16  = L & 15;
    const int quad = L >> 4;
    const int q    = w * 16 + n16;   // hidden col owned by this lane
    const int b0   = blockIdx.x * BT;

    // ---- stage x batch-major: xs[b][t] (512 f32x4, 2 per thread) ----
    #pragma unroll
    for (int k = 0; k < 2; ++k) {
        int idx = tid + k * 256;          // 0..511
        int row = idx >> 7;               // batch row 0..3
        int t4  = idx & 127;              // t/4
        f32x4 v = *(const f32x4*)(x + (size_t)(b0 + row) * TT + t4 * 4);
        *(f32x4*)(xs + row * XSTR + t4 * 4) = v;
    }
    // ---- zero both h buffers (256 dwords total) ----
    ((unsigned*)hbuf)[tid] = 0u;

    // ---- per-lane constants (gate scales folded) ----
    const float wr2   = -LOG2E  * Wih[q];
    const float wz2   = -LOG2E  * Wih[64 + q];
    const float wn2   =  LOG2E2 * Wih[128 + q];
    const float bR2   = -LOG2E  * (bih[q]      + bhh[q]);
    const float bZ2   = -LOG2E  * (bih[64 + q] + bhh[64 + q]);
    const float bN2   =  LOG2E2 * bhh[128 + q];
    const float bihn2 =  LOG2E2 * bih[128 + q];
    const float wo    = Wout[q];

    const f32x4 bR4   = {bR2, bR2, bR2, bR2};
    const f32x4 bZ4   = {bZ2, bZ2, bZ2, bZ2};
    const f32x4 bN4   = {bN2, bN2, bN2, bN2};
    const f32x4 zero4 = {0.f, 0.f, 0.f, 0.f};

    // ---- W_hh B-fragments (scaled), fp16 RNE ----
    f16x8 Bf[3][2];
    #pragma unroll
    for (int g = 0; g < 3; ++g) {
        const float sg = (g == 2) ? LOG2E2 : -LOG2E;
        #pragma unroll
        for (int c = 0; c < 2; ++c) {
            const float* p = Whh + ((g * 64 + q) * 64 + c * 32 + quad * 8);
            #pragma unroll
            for (int j = 0; j < 8; ++j)
                Bf[g][c][j] = (_Float16)(p[j] * sg);
        }
    }

    // persistent h (fp32): lane handles batch b = quad
    float hD  = 0.f;
    float hm1 = -1.f;   // h - 1, carried off-chain

    // dense exchange addressing
    const int waddr = ((q >> 3) * 4 + quad) * 8 + (q & 7);  // shorts
    const int rslot = quad * 4 + (n16 >> 2);                // s16x8 slots
    const s16x8* hbv = (const s16x8*)hbuf;
    const float* xrow = xs + quad * XSTR;

    // ---- anti-phase stagger for the 4 co-resident wgs ----
    {
        const int ph = (blockIdx.x >> 8) & 3;
        if      (ph == 1) __builtin_amdgcn_s_sleep(2);
        else if (ph == 2) __builtin_amdgcn_s_sleep(4);
        else if (ph == 3) __builtin_amdgcn_s_sleep(6);
    }

    auto step = [&](int cur, float xr_, float xz_, float xn_) {
        __syncthreads();

        s16x8 A0 = hbv[cur * 32 +      rslot];   // k  0..31
        s16x8 A1 = hbv[cur * 32 + 16 + rslot];   // k 32..63

        // R and N split (parallel MFMAs), Z chained (off critical path)
        f32x4 aRa = MFMA_F16(A0, Bf[0][0], bR4);
        f32x4 aRb = MFMA_F16(A1, Bf[0][1], zero4);
        f32x4 aNa = MFMA_F16(A0, Bf[2][0], bN4);
        f32x4 aNb = MFMA_F16(A1, Bf[2][1], zero4);
        f32x4 aZ  = MFMA_F16(A0, Bf[1][0], bZ4);
        aZ        = MFMA_F16(A1, Bf[1][1], aZ);

        float ar  = (xr_ + aRa[0]) + aRb[0];
        float Er  = __builtin_amdgcn_exp2f(ar);     // e^{-pre_r}
        float DR  = Er + 1.0f;
        float r   = __builtin_amdgcn_rcpf(DR);      // sigmoid(pre_r)
        float aN0 = aNa[0] + aNb[0];                // overlaps exp2/rcp
        float az  = xz_ + aZ[0];
        float Ez  = __builtin_amdgcn_exp2f(az);
        float DZ  = Ez + 1.0f;
        float an  = r * aN0 + xn_;                  // 2*log2e*pre_n
        float En  = __builtin_amdgcn_exp2f(an);
        float DN  = En + 1.0f;
        float P   = DZ * DN;
        float iq  = __builtin_amdgcn_rcpf(P);
        float rn  = iq * DZ;                        // 1/DN
        float z   = iq * DN;                        // 1/DZ = sigmoid(pre_z)
        float n   = rn * -2.0f + 1.0f;              // tanh(pre_n)
        float s   = rn *  2.0f + hm1;               // hp - n
        float hn  = z * s + n;                      // (1-z)n + z h

        hD  = hn;
        hm1 = hn - 1.0f;

        short* wh = (short*)hbuf + (cur ^ 1) * 256;
        _Float16 hf = (_Float16)hn;
        wh[waddr] = __builtin_bit_cast(short, hf);
    };

    for (int t = 0; t < TT; t += 4) {
        f32x4 xa = *(const f32x4*)(xrow + t);   // batch quad, steps t..t+3
        // precompute x terms off the recurrence chain
        float xr0 = xa[0] * wr2, xz0 = xa[0] * wz2, xn0 = xa[0] * wn2 + bihn2;
        float xr1 = xa[1] * wr2, xz1 = xa[1] * wz2, xn1 = xa[1] * wn2 + bihn2;
        float xr2 = xa[2] * wr2, xz2 = xa[2] * wz2, xn2 = xa[2] * wn2 + bihn2;
        float xr3 = xa[3] * wr2, xz3 = xa[3] * wz2, xn3 = xa[3] * wn2 + bihn2;
        step(0, xr0, xz0, xn0);
        step(1, xr1, xz1, xn1);
        step(0, xr2, xz2, xn2);
        step(1, xr3, xz3, xn3);
    }

    // ---- epilogue: out[b] = sum_q h[b][q]*Wout[q] + bout ----
    float p = hD * wo;
    p += __shfl_xor(p, 1, 64);
    p += __shfl_xor(p, 2, 64);
    p += __shfl_xor(p, 4, 64);
    p += __shfl_xor(p, 8, 64);
    if (n16 == 0) outp[w][quad] = p;
    __syncthreads();
    if (tid < BT) {
        out[b0 + tid] = outp[0][tid] + outp[1][tid] + outp[2][tid] + outp[3][tid] + bout[0];
    }
}

extern "C" void kernel_launch(void* const* d_in, const int* in_sizes, int n_in,
                              void* d_out, int out_size, void* d_ws, size_t ws_size,
                              hipStream_t stream) {
    (void)in_sizes; (void)n_in; (void)d_ws; (void)ws_size; (void)out_size;
    const float* x    = (const float*)d_in[0];
    const float* Wih  = (const float*)d_in[1];
    const float* Whh  = (const float*)d_in[2];
    const float* bih  = (const float*)d_in[3];
    const float* bhh  = (const float*)d_in[4];
    const float* Wout = (const float*)d_in[5];
    const float* bout = (const float*)d_in[6];
    float* out = (float*)d_out;

    gru_scan_kernel<<<dim3(4096 / BT), dim3(256), 0, stream>>>(
        x, Wih, Whh, bih, bhh, Wout, bout, out);
}